// Round 3
// baseline (7984.782 us; speedup 1.0000x reference)
//
#include <hip/hip_runtime.h>

typedef __bf16 bf16;
typedef short s16x4 __attribute__((ext_vector_type(4)));
typedef short s16x8 __attribute__((ext_vector_type(8)));
typedef float f32x4 __attribute__((ext_vector_type(4)));

#define MFMA16(a,b,c) __builtin_amdgcn_mfma_f32_16x16x32_bf16((a),(b),(c),0,0,0)

__device__ __forceinline__ float b2f(short s){
  union { float f; unsigned u; } v; v.u = ((unsigned)(unsigned short)s) << 16; return v.f;
}
__device__ __forceinline__ short f2b(float f){
  union { bf16 h; short s; } v; v.h = (bf16)f; return v.s;
}
__device__ __forceinline__ float sigm(float x){ return 1.f/(1.f+__expf(-x)); }
__device__ __forceinline__ float tanh_f(float x){ float e=__expf(2.f*x); return 1.f-2.f/(e+1.f); }
__device__ __forceinline__ float gelu_f(float x){ return 0.5f*x*(1.f+erff(x*0.70710678118654752f)); }
__device__ __forceinline__ float red16(float v){
  v += __shfl_xor(v,1); v += __shfl_xor(v,2); v += __shfl_xor(v,4); v += __shfl_xor(v,8);
  return v;
}

// ---- canonical bf16 workspace layout (element offsets past 16-byte flag header) ----
#define OFF_STATE   0         // [4096][128]
#define OFF_WENC    524288    // [256][128]
#define OFF_BENC    557056    // [256]
#define OFF_GENC    557312
#define OFF_BEENC   557568
#define OFF_WIH0E   557824    // [1024][256]  (Wih0[:, :256])
#define OFF_BACT    819968    // [1024][32]   (Wih0[:,256:260] zero-padded)
#define OFF_BIH0    852736
#define OFF_BHH0    853760
#define OFF_WHH0    854784    // [1024][256]
#define OFF_WIH1    1116928   // [1024][256]
#define OFF_WHH1    1379072   // [1024][256]
#define OFF_BIH1    1641216
#define OFF_BHH1    1642240
#define OFF_WD1     1643264   // [256][256]
#define OFF_BD1     1708800
#define OFF_GDEC    1709056
#define OFF_BEDEC   1709312
#define OFF_WD2     1709568   // [4][256]
#define OFF_BD2     1710592   // [4] (+4 pad)
#define N_CANON     1710600

// ---- dtype probe: state ~ N(0,1). bf16-packed words have bits14..7 = a bf16
// exponent (in [100,130] essentially always); f32 words have uniform mantissa
// bits there (~12% hit rate). 256 samples -> unambiguous.
__global__ __launch_bounds__(256) void detect_dtype(const unsigned* __restrict__ raw,
                                                    int* __restrict__ flag){
  unsigned w = raw[threadIdx.x];
  int e = (int)((w >> 7) & 0xFF);
  int looks_bf16 = (e >= 100 && e <= 130) ? 1 : 0;
  int cnt = __syncthreads_count(looks_bf16);
  if (threadIdx.x == 0) *flag = (cnt >= 128) ? 0 : 1;   // 1 => f32 buffers
}

__device__ __forceinline__ float ldf(const void* p, int i, int f32f){
  return f32f ? ((const float*)p)[i] : b2f(((const short*)p)[i]);
}

__global__ __launch_bounds__(256) void canonize(
    const void* state, const void* W_enc, const void* b_enc, const void* g_enc, const void* be_enc,
    const void* Wih0, const void* Whh0, const void* bih0, const void* bhh0,
    const void* Wih1, const void* Whh1, const void* bih1, const void* bhh1,
    const void* Wd1,  const void* bd1,  const void* g_dec, const void* be_dec,
    const void* Wd2,  const void* bd2,
    const int* __restrict__ flag, bf16* __restrict__ dst)
{
  int idx = blockIdx.x*256 + threadIdx.x;
  if (idx >= N_CANON) return;
  const int f = *flag;
  float v;
  if      (idx < OFF_WENC)  v = ldf(state, idx, f);
  else if (idx < OFF_BENC)  v = ldf(W_enc, idx-OFF_WENC, f);
  else if (idx < OFF_GENC)  v = ldf(b_enc, idx-OFF_BENC, f);
  else if (idx < OFF_BEENC) v = ldf(g_enc, idx-OFF_GENC, f);
  else if (idx < OFF_WIH0E) v = ldf(be_enc, idx-OFF_BEENC, f);
  else if (idx < OFF_BACT){ int j=idx-OFF_WIH0E; int r=j>>8, k=j&255; v = ldf(Wih0, r*260+k, f); }
  else if (idx < OFF_BIH0){ int j=idx-OFF_BACT;  int r=j>>5, k=j&31;  v = (k<4) ? ldf(Wih0, r*260+256+k, f) : 0.f; }
  else if (idx < OFF_BHH0)  v = ldf(bih0, idx-OFF_BIH0, f);
  else if (idx < OFF_WHH0)  v = ldf(bhh0, idx-OFF_BHH0, f);
  else if (idx < OFF_WIH1)  v = ldf(Whh0, idx-OFF_WHH0, f);
  else if (idx < OFF_WHH1)  v = ldf(Wih1, idx-OFF_WIH1, f);
  else if (idx < OFF_BIH1)  v = ldf(Whh1, idx-OFF_WHH1, f);
  else if (idx < OFF_BHH1)  v = ldf(bih1, idx-OFF_BIH1, f);
  else if (idx < OFF_WD1)   v = ldf(bhh1, idx-OFF_BHH1, f);
  else if (idx < OFF_BD1)   v = ldf(Wd1,  idx-OFF_WD1, f);
  else if (idx < OFF_GDEC)  v = ldf(bd1,  idx-OFF_BD1, f);
  else if (idx < OFF_BEDEC) v = ldf(g_dec, idx-OFF_GDEC, f);
  else if (idx < OFF_WD2)   v = ldf(be_dec, idx-OFF_BEDEC, f);
  else if (idx < OFF_BD2)   v = ldf(Wd2, idx-OFF_WD2, f);
  else { int j=idx-OFF_BD2; v = (j<4) ? ldf(bd2, j, f) : 0.f; }
  dst[idx] = (bf16)v;
}

// swizzled element index into a [32][256] bf16 LDS tile (xor 16B blocks by row&7)
__device__ __forceinline__ int swz(int row, int colOrKe){ return row*256 + (colOrKe ^ ((row&7)<<3)); }

__global__ __launch_bounds__(512, 2) void policy_main(
    const bf16* __restrict__ wsb, const int* __restrict__ flag, void* __restrict__ outv)
{
  __shared__ __align__(16) bf16 sh_h0[32*256];      // swizzled
  __shared__ __align__(16) bf16 sh_h1[32*256];      // swizzled
  __shared__ __align__(16) bf16 sh_emb[32*256];     // linear (prologue only)
  __shared__ __align__(16) bf16 sh_state[32*128];   // linear (prologue only)
  __shared__ __align__(16) bf16 sh_act[32*40];
  __shared__ float sh_red[8][32][2];
  __shared__ float sh_apart[8][32][4];
  __shared__ float sh_mu[32], sh_rs[32];

  const int tid  = threadIdx.x;
  const int wave = tid >> 6;
  const int lane = tid & 63;
  const int l15  = lane & 15;
  const int l4   = lane >> 4;
  const int jw   = wave * 32;
  const int rbase = blockIdx.x * 32;
  const int f32f = *flag;

  const bf16* stateW = wsb + OFF_STATE;
  const bf16* W_enc  = wsb + OFF_WENC;
  const bf16* b_enc  = wsb + OFF_BENC;
  const bf16* g_enc  = wsb + OFF_GENC;
  const bf16* be_enc = wsb + OFF_BEENC;
  const bf16* Wih0E  = wsb + OFF_WIH0E;
  const bf16* Bact   = wsb + OFF_BACT;
  const bf16* bih0   = wsb + OFF_BIH0;
  const bf16* bhh0   = wsb + OFF_BHH0;
  const bf16* Whh0   = wsb + OFF_WHH0;
  const bf16* Wih1   = wsb + OFF_WIH1;
  const bf16* Whh1   = wsb + OFF_WHH1;
  const bf16* bih1   = wsb + OFF_BIH1;
  const bf16* bhh1   = wsb + OFF_BHH1;
  const bf16* Wd1    = wsb + OFF_WD1;
  const bf16* bd1    = wsb + OFF_BD1;
  const bf16* g_dec  = wsb + OFF_GDEC;
  const bf16* be_dec = wsb + OFF_BEDEC;
  const bf16* Wd2g   = wsb + OFF_WD2;
  const bf16* bd2g   = wsb + OFF_BD2;

  // ---- prologue: init LDS ----
  for (int i = tid; i < 32*256; i += 512) { sh_h0[i]=(bf16)0.f; sh_h1[i]=(bf16)0.f; }
  for (int i = tid; i < 32*40; i += 512) sh_act[i]=(bf16)0.f;
  for (int i = tid; i < 32*128; i += 512) sh_state[i] = stateW[rbase*128 + i];
  __syncthreads();

  // ---- encoder GEMM: emb = state @ W_enc^T + b_enc; LN; GELU ----
  f32x4 eacc[2][2];
  #pragma unroll
  for (int m=0;m<2;m++)
    #pragma unroll
    for (int h=0;h<2;h++) eacc[m][h]=(f32x4){0.f,0.f,0.f,0.f};
  #pragma unroll
  for (int kk=0;kk<4;kk++){
    int ke = kk*32 + l4*8;
    s16x8 a0 = *(const s16x8*)(sh_state + l15*128 + ke);
    s16x8 a1 = *(const s16x8*)(sh_state + (16+l15)*128 + ke);
    #pragma unroll
    for (int h=0;h<2;h++){
      s16x8 b = *(const s16x8*)(W_enc + (jw + h*16 + l15)*128 + ke);
      eacc[0][h] = MFMA16(a0,b,eacc[0][h]);
      eacc[1][h] = MFMA16(a1,b,eacc[1][h]);
    }
  }
  #pragma unroll
  for (int h=0;h<2;h++){
    float be = b2f(((const short*)b_enc)[jw + h*16 + l15]);
    #pragma unroll
    for (int m=0;m<2;m++)
      #pragma unroll
      for (int r=0;r<4;r++) eacc[m][h][r] += be;
  }
  #pragma unroll
  for (int m=0;m<2;m++)
    #pragma unroll
    for (int r=0;r<4;r++){
      float v0=eacc[m][0][r], v1=eacc[m][1][r];
      float s = red16(v0+v1), q = red16(v0*v0+v1*v1);
      if (l15==0){ int row=m*16+l4*4+r; sh_red[wave][row][0]=s; sh_red[wave][row][1]=q; }
    }
  __syncthreads();
  if (tid < 32){
    float S=0.f,Q=0.f;
    #pragma unroll
    for (int w=0;w<8;w++){ S+=sh_red[w][tid][0]; Q+=sh_red[w][tid][1]; }
    float mu=S*(1.f/256.f), va=Q*(1.f/256.f)-mu*mu;
    sh_mu[tid]=mu; sh_rs[tid]=rsqrtf(va+1e-5f);
  }
  __syncthreads();
  {
    float ge[2]={b2f(((const short*)g_enc)[jw+l15]), b2f(((const short*)g_enc)[jw+16+l15])};
    float be2[2]={b2f(((const short*)be_enc)[jw+l15]), b2f(((const short*)be_enc)[jw+16+l15])};
    #pragma unroll
    for (int m=0;m<2;m++)
      #pragma unroll
      for (int h=0;h<2;h++)
        #pragma unroll
        for (int r=0;r<4;r++){
          int row=m*16+l4*4+r, col=jw+h*16+l15;
          float x=(eacc[m][h][r]-sh_mu[row])*sh_rs[row];
          x = x*ge[h]+be2[h];
          sh_emb[row*256+col] = (bf16)gelu_f(x);
        }
  }
  __syncthreads();

  // ---- z0const = Wih0[:, :256] @ emb^T + (bih0+bhh0), kept in packed-bf16 registers ----
  s16x4 zc0p[2][4][2];
  {
    f32x4 zc[2][4][2];
    #pragma unroll
    for (int m=0;m<2;m++)
      #pragma unroll
      for (int g=0;g<4;g++)
        #pragma unroll
        for (int h=0;h<2;h++) zc[m][g][h]=(f32x4){0.f,0.f,0.f,0.f};
    #pragma unroll
    for (int kk=0;kk<8;kk++){
      int ke=kk*32+l4*8;
      s16x8 a0=*(const s16x8*)(sh_emb + l15*256 + ke);
      s16x8 a1=*(const s16x8*)(sh_emb + (16+l15)*256 + ke);
      #pragma unroll
      for (int g=0;g<4;g++)
        #pragma unroll
        for (int h=0;h<2;h++){
          int c=g*256+jw+h*16+l15;
          s16x8 b = *(const s16x8*)(Wih0E + c*256 + ke);
          zc[0][g][h]=MFMA16(a0,b,zc[0][g][h]);
          zc[1][g][h]=MFMA16(a1,b,zc[1][g][h]);
        }
    }
    #pragma unroll
    for (int g=0;g<4;g++)
      #pragma unroll
      for (int h=0;h<2;h++){
        int c=g*256+jw+h*16+l15;
        float bb=b2f(((const short*)bih0)[c])+b2f(((const short*)bhh0)[c]);
        #pragma unroll
        for (int m=0;m<2;m++){
          s16x4 pk;
          #pragma unroll
          for (int r=0;r<4;r++) pk[r]=f2b(zc[m][g][h][r]+bb);
          zc0p[m][g][h]=pk;
        }
      }
  }

  // ---- persistent per-thread parameters ----
  float bz1f[4][2];
  #pragma unroll
  for (int g=0;g<4;g++)
    #pragma unroll
    for (int h=0;h<2;h++){
      int c=g*256+jw+h*16+l15;
      bz1f[g][h]=b2f(((const short*)bih1)[c])+b2f(((const short*)bhh1)[c]);
    }
  float bd1f[2]={b2f(((const short*)bd1)[jw+l15]), b2f(((const short*)bd1)[jw+16+l15])};
  float gdec[2]={b2f(((const short*)g_dec)[jw+l15]), b2f(((const short*)g_dec)[jw+16+l15])};
  float bdec[2]={b2f(((const short*)be_dec)[jw+l15]), b2f(((const short*)be_dec)[jw+16+l15])};
  float wd2f[4][2];
  #pragma unroll
  for (int a=0;a<4;a++){
    wd2f[a][0]=b2f(((const short*)Wd2g)[a*256+jw+l15]);
    wd2f[a][1]=b2f(((const short*)Wd2g)[a*256+jw+16+l15]);
  }
  float bd2v = b2f(((const short*)bd2g)[tid&3]);
  float c0r[2][2][4], c1r[2][2][4];
  #pragma unroll
  for (int m=0;m<2;m++)
    #pragma unroll
    for (int h=0;h<2;h++)
      #pragma unroll
      for (int r=0;r<4;r++){ c0r[m][h][r]=0.f; c1r[m][h][r]=0.f; }
  __syncthreads();

  // ================= 64 recurrent steps =================
  for (int t=0;t<64;++t){
    // ---------- layer0: z0 = z0const + Whh0 @ h0 + Bact @ act ----------
    f32x4 acc[2][4][2];
    #pragma unroll
    for (int m=0;m<2;m++)
      #pragma unroll
      for (int g=0;g<4;g++)
        #pragma unroll
        for (int h=0;h<2;h++){
          s16x4 z=zc0p[m][g][h];
          acc[m][g][h]=(f32x4){b2f(z[0]),b2f(z[1]),b2f(z[2]),b2f(z[3])};
        }
    #pragma unroll
    for (int kk=0;kk<9;kk++){
      s16x8 a0,a1;
      if (kk<8){
        int ke=kk*32+l4*8;
        a0=*(const s16x8*)(sh_h0 + swz(l15,ke));
        a1=*(const s16x8*)(sh_h0 + swz(16+l15,ke));
      } else {
        a0=*(const s16x8*)(sh_act + l15*40 + l4*8);
        a1=*(const s16x8*)(sh_act + (16+l15)*40 + l4*8);
      }
      #pragma unroll
      for (int g=0;g<4;g++)
        #pragma unroll
        for (int h=0;h<2;h++){
          int c=g*256+jw+h*16+l15;
          s16x8 b = (kk<8) ? *(const s16x8*)(Whh0 + c*256 + kk*32 + l4*8)
                           : *(const s16x8*)(Bact + c*32 + l4*8);
          acc[0][g][h]=MFMA16(a0,b,acc[0][g][h]);
          acc[1][g][h]=MFMA16(a1,b,acc[1][g][h]);
        }
    }
    float hnew[2][2][4];
    #pragma unroll
    for (int m=0;m<2;m++)
      #pragma unroll
      for (int h=0;h<2;h++)
        #pragma unroll
        for (int r=0;r<4;r++){
          float cn = sigm(acc[m][1][h][r])*c0r[m][h][r] + sigm(acc[m][0][h][r])*tanh_f(acc[m][2][h][r]);
          c0r[m][h][r]=cn;
          hnew[m][h][r]=sigm(acc[m][3][h][r])*tanh_f(cn);
        }
    __syncthreads();
    #pragma unroll
    for (int m=0;m<2;m++)
      #pragma unroll
      for (int h=0;h<2;h++)
        #pragma unroll
        for (int r=0;r<4;r++){
          int row=m*16+l4*4+r, col=jw+h*16+l15;
          sh_h0[swz(row,col)] = (bf16)hnew[m][h][r];
        }
    __syncthreads();

    // ---------- layer1: z1 = bz1 + Wih1 @ h0_new + Whh1 @ h1_old ----------
    #pragma unroll
    for (int m=0;m<2;m++)
      #pragma unroll
      for (int g=0;g<4;g++)
        #pragma unroll
        for (int h=0;h<2;h++){
          float bb=bz1f[g][h];
          acc[m][g][h]=(f32x4){bb,bb,bb,bb};
        }
    #pragma unroll
    for (int kk=0;kk<16;kk++){
      s16x8 a0,a1;
      if (kk<8){
        int ke=kk*32+l4*8;
        a0=*(const s16x8*)(sh_h0 + swz(l15,ke));
        a1=*(const s16x8*)(sh_h0 + swz(16+l15,ke));
      } else {
        int ke=(kk-8)*32+l4*8;
        a0=*(const s16x8*)(sh_h1 + swz(l15,ke));
        a1=*(const s16x8*)(sh_h1 + swz(16+l15,ke));
      }
      #pragma unroll
      for (int g=0;g<4;g++)
        #pragma unroll
        for (int h=0;h<2;h++){
          int c=g*256+jw+h*16+l15;
          s16x8 b = (kk<8) ? *(const s16x8*)(Wih1 + c*256 + kk*32 + l4*8)
                           : *(const s16x8*)(Whh1 + c*256 + (kk-8)*32 + l4*8);
          acc[0][g][h]=MFMA16(a0,b,acc[0][g][h]);
          acc[1][g][h]=MFMA16(a1,b,acc[1][g][h]);
        }
    }
    #pragma unroll
    for (int m=0;m<2;m++)
      #pragma unroll
      for (int h=0;h<2;h++)
        #pragma unroll
        for (int r=0;r<4;r++){
          float cn = sigm(acc[m][1][h][r])*c1r[m][h][r] + sigm(acc[m][0][h][r])*tanh_f(acc[m][2][h][r]);
          c1r[m][h][r]=cn;
          hnew[m][h][r]=sigm(acc[m][3][h][r])*tanh_f(cn);
        }
    __syncthreads();
    #pragma unroll
    for (int m=0;m<2;m++)
      #pragma unroll
      for (int h=0;h<2;h++)
        #pragma unroll
        for (int r=0;r<4;r++){
          int row=m*16+l4*4+r, col=jw+h*16+l15;
          sh_h1[swz(row,col)] = (bf16)hnew[m][h][r];
        }
    __syncthreads();

    // ---------- decoder ----------
    f32x4 dacc[2][2];
    #pragma unroll
    for (int m=0;m<2;m++)
      #pragma unroll
      for (int h=0;h<2;h++){
        float bb=bd1f[h];
        dacc[m][h]=(f32x4){bb,bb,bb,bb};
      }
    #pragma unroll
    for (int kk=0;kk<8;kk++){
      int ke=kk*32+l4*8;
      s16x8 a0=*(const s16x8*)(sh_h1 + swz(l15,ke));
      s16x8 a1=*(const s16x8*)(sh_h1 + swz(16+l15,ke));
      #pragma unroll
      for (int h=0;h<2;h++){
        int c=jw+h*16+l15;
        s16x8 b=*(const s16x8*)(Wd1 + c*256 + kk*32 + l4*8);
        dacc[0][h]=MFMA16(a0,b,dacc[0][h]);
        dacc[1][h]=MFMA16(a1,b,dacc[1][h]);
      }
    }
    #pragma unroll
    for (int m=0;m<2;m++)
      #pragma unroll
      for (int r=0;r<4;r++){
        float v0=dacc[m][0][r], v1=dacc[m][1][r];
        float s=red16(v0+v1), q=red16(v0*v0+v1*v1);
        if (l15==0){ int row=m*16+l4*4+r; sh_red[wave][row][0]=s; sh_red[wave][row][1]=q; }
      }
    __syncthreads();
    if (tid<32){
      float S=0.f,Q=0.f;
      #pragma unroll
      for (int w=0;w<8;w++){ S+=sh_red[w][tid][0]; Q+=sh_red[w][tid][1]; }
      float mu=S*(1.f/256.f), va=Q*(1.f/256.f)-mu*mu;
      sh_mu[tid]=mu; sh_rs[tid]=rsqrtf(va+1e-5f);
    }
    __syncthreads();
    float yv[2][2][4];
    #pragma unroll
    for (int m=0;m<2;m++)
      #pragma unroll
      for (int h=0;h<2;h++)
        #pragma unroll
        for (int r=0;r<4;r++){
          int row=m*16+l4*4+r;
          float x=(dacc[m][h][r]-sh_mu[row])*sh_rs[row];
          x = x*gdec[h]+bdec[h];
          yv[m][h][r]=gelu_f(x);
        }
    #pragma unroll
    for (int m=0;m<2;m++)
      #pragma unroll
      for (int r=0;r<4;r++){
        int row=m*16+l4*4+r;
        #pragma unroll
        for (int a=0;a<4;a++){
          float p = yv[m][0][r]*wd2f[a][0] + yv[m][1][r]*wd2f[a][1];
          p = red16(p);
          if (l15==0) sh_apart[wave][row][a]=p;
        }
      }
    __syncthreads();
    if (tid<128){
      int row=tid>>2, a=tid&3;
      float s=bd2v;
      #pragma unroll
      for (int w=0;w<8;w++) s+=sh_apart[w][row][a];
      bf16 ab=(bf16)s;
      sh_act[row*40+a]=ab;
      size_t oi=((size_t)(rbase+row)*64 + t)*4 + a;
      if (f32f) ((float*)outv)[oi]=s; else ((bf16*)outv)[oi]=ab;
    }
    __syncthreads();
  }

  // ---- final h, c outputs ----
  if (f32f){
    float* o=(float*)outv;
    for (int i=tid;i<32*256;i+=512){
      int row=i>>8, col=i&255;
      int sw = swz(row,col);
      o[1048576 + (size_t)(rbase+row)*256 + col] = b2f(((const short*)sh_h0)[sw]);
      o[2097152 + (size_t)(rbase+row)*256 + col] = b2f(((const short*)sh_h1)[sw]);
    }
    #pragma unroll
    for (int m=0;m<2;m++)
      #pragma unroll
      for (int h=0;h<2;h++)
        #pragma unroll
        for (int r=0;r<4;r++){
          int row=m*16+l4*4+r, col=jw+h*16+l15;
          o[3145728 + (size_t)(rbase+row)*256 + col] = c0r[m][h][r];
          o[4194304 + (size_t)(rbase+row)*256 + col] = c1r[m][h][r];
        }
  } else {
    bf16* o=(bf16*)outv;
    for (int i=tid;i<32*256;i+=512){
      int row=i>>8, col=i&255;
      int sw = swz(row,col);
      o[1048576 + (size_t)(rbase+row)*256 + col] = sh_h0[sw];
      o[2097152 + (size_t)(rbase+row)*256 + col] = sh_h1[sw];
    }
    #pragma unroll
    for (int m=0;m<2;m++)
      #pragma unroll
      for (int h=0;h<2;h++)
        #pragma unroll
        for (int r=0;r<4;r++){
          int row=m*16+l4*4+r, col=jw+h*16+l15;
          o[3145728 + (size_t)(rbase+row)*256 + col] = (bf16)c0r[m][h][r];
          o[4194304 + (size_t)(rbase+row)*256 + col] = (bf16)c1r[m][h][r];
        }
  }
}

extern "C" void kernel_launch(void* const* d_in, const int* in_sizes, int n_in,
                              void* d_out, int out_size, void* d_ws, size_t ws_size,
                              hipStream_t stream) {
  int* flag = (int*)d_ws;                      // 16-byte header
  bf16* wsb = (bf16*)d_ws + 8;                 // canonical bf16 region (~3.35 MB)

  detect_dtype<<<1, 256, 0, stream>>>((const unsigned*)d_in[0], flag);

  canonize<<<(N_CANON+255)/256, 256, 0, stream>>>(
      d_in[0],  d_in[2],  d_in[3],  d_in[4],  d_in[5],
      d_in[6],  d_in[7],  d_in[8],  d_in[9],
      d_in[10], d_in[11], d_in[12], d_in[13],
      d_in[14], d_in[15], d_in[16], d_in[17],
      d_in[18], d_in[19],
      flag, wsb);

  policy_main<<<128, 512, 0, stream>>>(wsb, flag, d_out);
}

// Round 4
// 7633.321 us; speedup vs baseline: 1.0460x; 1.0460x over previous
//
#include <hip/hip_runtime.h>

typedef __bf16 bf16;
typedef short s16x4 __attribute__((ext_vector_type(4)));
typedef short s16x8 __attribute__((ext_vector_type(8)));
typedef float f32x4 __attribute__((ext_vector_type(4)));

#define MFMA16(a,b,c) __builtin_amdgcn_mfma_f32_16x16x32_bf16((a),(b),(c),0,0,0)

__device__ __forceinline__ float b2f(short s){
  union { float f; unsigned u; } v; v.u = ((unsigned)(unsigned short)s) << 16; return v.f;
}
__device__ __forceinline__ short f2b(float f){
  union { bf16 h; short s; } v; v.h = (bf16)f; return v.s;
}
__device__ __forceinline__ float sigm(float x){ return 1.f/(1.f+__expf(-x)); }
__device__ __forceinline__ float tanh_f(float x){ float e=__expf(2.f*x); return 1.f-2.f/(e+1.f); }
__device__ __forceinline__ float gelu_f(float x){ return 0.5f*x*(1.f+erff(x*0.70710678118654752f)); }
__device__ __forceinline__ float red16(float v){
  v += __shfl_xor(v,1); v += __shfl_xor(v,2); v += __shfl_xor(v,4); v += __shfl_xor(v,8);
  return v;
}

// ---- canonical bf16 workspace layout (element offsets past 16-byte flag header) ----
#define OFF_STATE   0         // [4096][128]
#define OFF_WENC    524288    // [256][128]
#define OFF_BENC    557056
#define OFF_GENC    557312
#define OFF_BEENC   557568
#define OFF_WIH0E   557824    // [1024][256]  (Wih0[:, :256], prologue only)
#define OFF_W0E     819968    // [1024][288]  ([Whh0 | Wact(4) zero-pad to 32])
#define OFF_BIH0    1114880
#define OFF_BHH0    1115904
#define OFF_W1C     1116928   // [1024][512]  ([Wih1 | Whh1])
#define OFF_BIH1    1641216
#define OFF_BHH1    1642240
#define OFF_WD1     1643264   // [256][256]
#define OFF_BD1     1708800
#define OFF_GDEC    1709056
#define OFF_BEDEC   1709312
#define OFF_WD2     1709568   // [4][256]
#define OFF_BD2     1710592   // [4] (+4 pad)
#define N_CANON     1710600

__global__ __launch_bounds__(256) void detect_dtype(const unsigned* __restrict__ raw,
                                                    int* __restrict__ flag){
  unsigned w = raw[threadIdx.x];
  int e = (int)((w >> 7) & 0xFF);
  int looks_bf16 = (e >= 100 && e <= 130) ? 1 : 0;
  int cnt = __syncthreads_count(looks_bf16);
  if (threadIdx.x == 0) *flag = (cnt >= 128) ? 0 : 1;   // 1 => f32 buffers
}

__device__ __forceinline__ float ldf(const void* p, int i, int f32f){
  return f32f ? ((const float*)p)[i] : b2f(((const short*)p)[i]);
}

__global__ __launch_bounds__(256) void canonize(
    const void* state, const void* W_enc, const void* b_enc, const void* g_enc, const void* be_enc,
    const void* Wih0, const void* Whh0, const void* bih0, const void* bhh0,
    const void* Wih1, const void* Whh1, const void* bih1, const void* bhh1,
    const void* Wd1,  const void* bd1,  const void* g_dec, const void* be_dec,
    const void* Wd2,  const void* bd2,
    const int* __restrict__ flag, bf16* __restrict__ dst)
{
  int idx = blockIdx.x*256 + threadIdx.x;
  if (idx >= N_CANON) return;
  const int f = *flag;
  float v;
  if      (idx < OFF_WENC)  v = ldf(state, idx, f);
  else if (idx < OFF_BENC)  v = ldf(W_enc, idx-OFF_WENC, f);
  else if (idx < OFF_GENC)  v = ldf(b_enc, idx-OFF_BENC, f);
  else if (idx < OFF_BEENC) v = ldf(g_enc, idx-OFF_GENC, f);
  else if (idx < OFF_WIH0E) v = ldf(be_enc, idx-OFF_BEENC, f);
  else if (idx < OFF_W0E){  int j=idx-OFF_WIH0E; int r=j>>8, k=j&255; v = ldf(Wih0, r*260+k, f); }
  else if (idx < OFF_BIH0){ int j=idx-OFF_W0E;   int r=j/288, k=j-r*288;
                            v = (k<256) ? ldf(Whh0, r*256+k, f)
                              : (k<260) ? ldf(Wih0, r*260+256+(k-256), f) : 0.f; }
  else if (idx < OFF_BHH0)  v = ldf(bih0, idx-OFF_BIH0, f);
  else if (idx < OFF_W1C)   v = ldf(bhh0, idx-OFF_BHH0, f);
  else if (idx < OFF_BIH1){ int j=idx-OFF_W1C; int r=j>>9, k=j&511;
                            v = (k<256) ? ldf(Wih1, r*256+k, f) : ldf(Whh1, r*256+(k-256), f); }
  else if (idx < OFF_BHH1)  v = ldf(bih1, idx-OFF_BIH1, f);
  else if (idx < OFF_WD1)   v = ldf(bhh1, idx-OFF_BHH1, f);
  else if (idx < OFF_BD1)   v = ldf(Wd1,  idx-OFF_WD1, f);
  else if (idx < OFF_GDEC)  v = ldf(bd1,  idx-OFF_BD1, f);
  else if (idx < OFF_BEDEC) v = ldf(g_dec, idx-OFF_GDEC, f);
  else if (idx < OFF_WD2)   v = ldf(be_dec, idx-OFF_BEDEC, f);
  else if (idx < OFF_BD2)   v = ldf(Wd2, idx-OFF_WD2, f);
  else { int j=idx-OFF_BD2; v = (j<4) ? ldf(bd2, j, f) : 0.f; }
  dst[idx] = (bf16)v;
}

// swizzled element index into a [32][256] bf16 LDS tile (xor 16B blocks by row&7)
__device__ __forceinline__ int swz(int row, int colOrKe){ return row*256 + (colOrKe ^ ((row&7)<<3)); }

// load the 8 (g,h) B-fragments for one K-subtile
template<int STRIDE>
__device__ __forceinline__ void loadB8(s16x8* buf, const bf16* W, int cb, int koff){
  #pragma unroll
  for (int g=0;g<4;g++)
    #pragma unroll
    for (int h=0;h<2;h++)
      buf[g*2+h] = *(const s16x8*)(W + (size_t)(g*256 + cb + h*16)*STRIDE + koff);
}

__device__ __forceinline__ void mfma16x(f32x4 (&acc)[2][4][2], s16x8 a0, s16x8 a1, const s16x8* bb){
  #pragma unroll
  for (int g=0;g<4;g++)
    #pragma unroll
    for (int h=0;h<2;h++){
      acc[0][g][h]=MFMA16(a0,bb[g*2+h],acc[0][g][h]);
      acc[1][g][h]=MFMA16(a1,bb[g*2+h],acc[1][g][h]);
    }
}

__global__ __launch_bounds__(512) void policy_main(
    const bf16* __restrict__ wsb, const int* __restrict__ flag, void* __restrict__ outv)
{
  __shared__ __align__(16) bf16 sh_h0[32*256];        // swizzled
  __shared__ __align__(16) bf16 sh_h1[32*256];        // swizzled
  __shared__ __align__(16) bf16 sh_act[32*40];
  __shared__ __align__(16) s16x4 sh_zc[16][512];      // z0const, [frag][tid]
  __shared__ __align__(16) bf16 sh_actout[32*256];    // action buffer [row][t*4+a]
  __shared__ __align__(16) bf16 sh_emb[32*256];       // prologue only
  __shared__ __align__(16) bf16 sh_state[32*128];     // prologue only
  __shared__ float sh_red[8][32][2];
  __shared__ float sh_apart[8][32][4];
  __shared__ float sh_mu[32], sh_rs[32];

  const int tid  = threadIdx.x;
  const int wave = tid >> 6;
  const int lane = tid & 63;
  const int l15  = lane & 15;
  const int l4   = lane >> 4;
  const int jw   = wave * 32;
  const int cb   = jw + l15;            // base gate-col for this lane
  const int rbase = blockIdx.x * 32;
  const int f32f = *flag;

  const bf16* stateW = wsb + OFF_STATE;
  const bf16* W_enc  = wsb + OFF_WENC;
  const bf16* W0E    = wsb + OFF_W0E;
  const bf16* W1C    = wsb + OFF_W1C;
  const bf16* Wd1    = wsb + OFF_WD1;
  const bf16* Wih0E  = wsb + OFF_WIH0E;

  // ---- prologue: init LDS ----
  for (int i = tid; i < 32*256; i += 512) { sh_h0[i]=(bf16)0.f; sh_h1[i]=(bf16)0.f; }
  for (int i = tid; i < 32*40; i += 512) sh_act[i]=(bf16)0.f;
  for (int i = tid; i < 32*128; i += 512) sh_state[i] = stateW[rbase*128 + i];
  __syncthreads();

  // ---- encoder GEMM: emb = state @ W_enc^T + b_enc; LN; GELU ----
  f32x4 eacc[2][2];
  #pragma unroll
  for (int m=0;m<2;m++)
    #pragma unroll
    for (int h=0;h<2;h++) eacc[m][h]=(f32x4){0.f,0.f,0.f,0.f};
  #pragma unroll
  for (int kk=0;kk<4;kk++){
    int ke = kk*32 + l4*8;
    s16x8 a0 = *(const s16x8*)(sh_state + l15*128 + ke);
    s16x8 a1 = *(const s16x8*)(sh_state + (16+l15)*128 + ke);
    #pragma unroll
    for (int h=0;h<2;h++){
      s16x8 b = *(const s16x8*)(W_enc + (jw + h*16 + l15)*128 + ke);
      eacc[0][h] = MFMA16(a0,b,eacc[0][h]);
      eacc[1][h] = MFMA16(a1,b,eacc[1][h]);
    }
  }
  #pragma unroll
  for (int h=0;h<2;h++){
    float be = b2f(((const short*)(wsb+OFF_BENC))[jw + h*16 + l15]);
    #pragma unroll
    for (int m=0;m<2;m++)
      #pragma unroll
      for (int r=0;r<4;r++) eacc[m][h][r] += be;
  }
  #pragma unroll
  for (int m=0;m<2;m++)
    #pragma unroll
    for (int r=0;r<4;r++){
      float v0=eacc[m][0][r], v1=eacc[m][1][r];
      float s = red16(v0+v1), q = red16(v0*v0+v1*v1);
      if (l15==0){ int row=m*16+l4*4+r; sh_red[wave][row][0]=s; sh_red[wave][row][1]=q; }
    }
  __syncthreads();
  if (tid < 32){
    float S=0.f,Q=0.f;
    #pragma unroll
    for (int w=0;w<8;w++){ S+=sh_red[w][tid][0]; Q+=sh_red[w][tid][1]; }
    float mu=S*(1.f/256.f), va=Q*(1.f/256.f)-mu*mu;
    sh_mu[tid]=mu; sh_rs[tid]=rsqrtf(va+1e-5f);
  }
  __syncthreads();
  {
    float ge[2]={b2f(((const short*)(wsb+OFF_GENC))[jw+l15]), b2f(((const short*)(wsb+OFF_GENC))[jw+16+l15])};
    float be2[2]={b2f(((const short*)(wsb+OFF_BEENC))[jw+l15]), b2f(((const short*)(wsb+OFF_BEENC))[jw+16+l15])};
    #pragma unroll
    for (int m=0;m<2;m++)
      #pragma unroll
      for (int h=0;h<2;h++)
        #pragma unroll
        for (int r=0;r<4;r++){
          int row=m*16+l4*4+r, col=jw+h*16+l15;
          float x=(eacc[m][h][r]-sh_mu[row])*sh_rs[row];
          x = x*ge[h]+be2[h];
          sh_emb[row*256+col] = (bf16)gelu_f(x);
        }
  }
  __syncthreads();

  // ---- z0const = Wih0[:, :256] @ emb^T + (bih0+bhh0) -> sh_zc (packed bf16) ----
  {
    f32x4 zc[2][4][2];
    #pragma unroll
    for (int m=0;m<2;m++)
      #pragma unroll
      for (int g=0;g<4;g++)
        #pragma unroll
        for (int h=0;h<2;h++) zc[m][g][h]=(f32x4){0.f,0.f,0.f,0.f};
    #pragma unroll
    for (int kk=0;kk<8;kk++){
      int ke=kk*32+l4*8;
      s16x8 a0=*(const s16x8*)(sh_emb + l15*256 + ke);
      s16x8 a1=*(const s16x8*)(sh_emb + (16+l15)*256 + ke);
      #pragma unroll
      for (int g=0;g<4;g++)
        #pragma unroll
        for (int h=0;h<2;h++){
          int c=g*256+cb+h*16;
          s16x8 b = *(const s16x8*)(Wih0E + c*256 + ke);
          zc[0][g][h]=MFMA16(a0,b,zc[0][g][h]);
          zc[1][g][h]=MFMA16(a1,b,zc[1][g][h]);
        }
    }
    #pragma unroll
    for (int g=0;g<4;g++)
      #pragma unroll
      for (int h=0;h<2;h++){
        int c=g*256+cb+h*16;
        float bb=b2f(((const short*)(wsb+OFF_BIH0))[c])+b2f(((const short*)(wsb+OFF_BHH0))[c]);
        #pragma unroll
        for (int m=0;m<2;m++){
          s16x4 pk;
          #pragma unroll
          for (int r=0;r<4;r++) pk[r]=f2b(zc[m][g][h][r]+bb);
          sh_zc[m*8+g*2+h][tid]=pk;
        }
      }
  }

  // ---- persistent per-thread parameters ----
  float bz1f[4][2];
  #pragma unroll
  for (int g=0;g<4;g++)
    #pragma unroll
    for (int h=0;h<2;h++){
      int c=g*256+cb+h*16;
      bz1f[g][h]=b2f(((const short*)(wsb+OFF_BIH1))[c])+b2f(((const short*)(wsb+OFF_BHH1))[c]);
    }
  float bd1f[2]={b2f(((const short*)(wsb+OFF_BD1))[jw+l15]), b2f(((const short*)(wsb+OFF_BD1))[jw+16+l15])};
  float gdec[2]={b2f(((const short*)(wsb+OFF_GDEC))[jw+l15]), b2f(((const short*)(wsb+OFF_GDEC))[jw+16+l15])};
  float bdec[2]={b2f(((const short*)(wsb+OFF_BEDEC))[jw+l15]), b2f(((const short*)(wsb+OFF_BEDEC))[jw+16+l15])};
  float wd2f[4][2];
  #pragma unroll
  for (int a=0;a<4;a++){
    wd2f[a][0]=b2f(((const short*)(wsb+OFF_WD2))[a*256+jw+l15]);
    wd2f[a][1]=b2f(((const short*)(wsb+OFF_WD2))[a*256+jw+16+l15]);
  }
  float bd2v = b2f(((const short*)(wsb+OFF_BD2))[tid&3]);
  float c0r[2][2][4], c1r[2][2][4];
  #pragma unroll
  for (int m=0;m<2;m++)
    #pragma unroll
    for (int h=0;h<2;h++)
      #pragma unroll
      for (int r=0;r<4;r++){ c0r[m][h][r]=0.f; c1r[m][h][r]=0.f; }
  __syncthreads();

  // ---- weight-fragment double buffers + first prefetch (L0 kk=0) ----
  s16x8 bb0[8], bb1[8];
  const int koff = l4*8;
  loadB8<288>(bb0, W0E, cb, koff);

  // ================= 64 recurrent steps =================
  #pragma unroll 1
  for (int t=0;t<64;++t){
    // ---------- layer0: z0 = z0const + [Whh0|Wact] @ [h0|act] ----------
    f32x4 acc[2][4][2];
    #pragma unroll
    for (int m=0;m<2;m++)
      #pragma unroll
      for (int g=0;g<4;g++)
        #pragma unroll
        for (int h=0;h<2;h++){
          s16x4 z=sh_zc[m*8+g*2+h][tid];
          acc[m][g][h]=(f32x4){b2f(z[0]),b2f(z[1]),b2f(z[2]),b2f(z[3])};
        }
    #pragma unroll
    for (int kk=0;kk<9;kk++){
      if (kk+1 < 9) loadB8<288>(((kk&1)?bb0:bb1), W0E, cb, (kk+1)*32+koff);
      s16x8 a0,a1;
      if (kk<8){
        int ke=kk*32+koff;
        a0=*(const s16x8*)(sh_h0 + swz(l15,ke));
        a1=*(const s16x8*)(sh_h0 + swz(16+l15,ke));
      } else {
        a0=*(const s16x8*)(sh_act + l15*40 + koff);
        a1=*(const s16x8*)(sh_act + (16+l15)*40 + koff);
      }
      mfma16x(acc, a0, a1, ((kk&1)?bb1:bb0));
    }
    loadB8<512>(bb0, W1C, cb, koff);           // prefetch layer1 kk=0 (hidden under gates+barriers)
    float hnew[2][2][4];
    #pragma unroll
    for (int m=0;m<2;m++)
      #pragma unroll
      for (int h=0;h<2;h++)
        #pragma unroll
        for (int r=0;r<4;r++){
          float cn = sigm(acc[m][1][h][r])*c0r[m][h][r] + sigm(acc[m][0][h][r])*tanh_f(acc[m][2][h][r]);
          c0r[m][h][r]=cn;
          hnew[m][h][r]=sigm(acc[m][3][h][r])*tanh_f(cn);
        }
    __syncthreads();
    #pragma unroll
    for (int m=0;m<2;m++)
      #pragma unroll
      for (int h=0;h<2;h++)
        #pragma unroll
        for (int r=0;r<4;r++){
          int row=m*16+l4*4+r, col=jw+h*16+l15;
          sh_h0[swz(row,col)] = (bf16)hnew[m][h][r];
        }
    __syncthreads();

    // ---------- layer1: z1 = bz1 + [Wih1|Whh1] @ [h0|h1] ----------
    #pragma unroll
    for (int m=0;m<2;m++)
      #pragma unroll
      for (int g=0;g<4;g++)
        #pragma unroll
        for (int h=0;h<2;h++){
          float bbv=bz1f[g][h];
          acc[m][g][h]=(f32x4){bbv,bbv,bbv,bbv};
        }
    #pragma unroll
    for (int kk=0;kk<16;kk++){
      if (kk+1 < 16) loadB8<512>(((kk&1)?bb0:bb1), W1C, cb, (kk+1)*32+koff);
      s16x8 a0,a1;
      if (kk<8){
        int ke=kk*32+koff;
        a0=*(const s16x8*)(sh_h0 + swz(l15,ke));
        a1=*(const s16x8*)(sh_h0 + swz(16+l15,ke));
      } else {
        int ke=(kk-8)*32+koff;
        a0=*(const s16x8*)(sh_h1 + swz(l15,ke));
        a1=*(const s16x8*)(sh_h1 + swz(16+l15,ke));
      }
      mfma16x(acc, a0, a1, ((kk&1)?bb1:bb0));
    }
    // prefetch ALL of this wave's Wd1 fragments (16) — hidden under gates+barriers
    #pragma unroll
    for (int kk=0;kk<8;kk++)
      #pragma unroll
      for (int hh=0;hh<2;hh++){
        int c = cb + hh*16;
        ((kk<4)?bb0:bb1)[(kk&3)*2+hh] = *(const s16x8*)(Wd1 + c*256 + kk*32 + koff);
      }
    #pragma unroll
    for (int m=0;m<2;m++)
      #pragma unroll
      for (int h=0;h<2;h++)
        #pragma unroll
        for (int r=0;r<4;r++){
          float cn = sigm(acc[m][1][h][r])*c1r[m][h][r] + sigm(acc[m][0][h][r])*tanh_f(acc[m][2][h][r]);
          c1r[m][h][r]=cn;
          hnew[m][h][r]=sigm(acc[m][3][h][r])*tanh_f(cn);
        }
    __syncthreads();
    #pragma unroll
    for (int m=0;m<2;m++)
      #pragma unroll
      for (int h=0;h<2;h++)
        #pragma unroll
        for (int r=0;r<4;r++){
          int row=m*16+l4*4+r, col=jw+h*16+l15;
          sh_h1[swz(row,col)] = (bf16)hnew[m][h][r];
        }
    __syncthreads();

    // ---------- decoder: d1 = bd1 + Wd1 @ h1_new (frags already in regs) ----------
    f32x4 dacc[2][2];
    #pragma unroll
    for (int m=0;m<2;m++)
      #pragma unroll
      for (int h=0;h<2;h++){
        float bbv=bd1f[h];
        dacc[m][h]=(f32x4){bbv,bbv,bbv,bbv};
      }
    #pragma unroll
    for (int kk=0;kk<8;kk++){
      int ke=kk*32+koff;
      s16x8 a0=*(const s16x8*)(sh_h1 + swz(l15,ke));
      s16x8 a1=*(const s16x8*)(sh_h1 + swz(16+l15,ke));
      #pragma unroll
      for (int hh=0;hh<2;hh++){
        s16x8 b = ((kk<4)?bb0:bb1)[(kk&3)*2+hh];
        dacc[0][hh]=MFMA16(a0,b,dacc[0][hh]);
        dacc[1][hh]=MFMA16(a1,b,dacc[1][hh]);
      }
    }
    loadB8<288>(bb0, W0E, cb, koff);           // prefetch next step's L0 kk=0
    #pragma unroll
    for (int m=0;m<2;m++)
      #pragma unroll
      for (int r=0;r<4;r++){
        float v0=dacc[m][0][r], v1=dacc[m][1][r];
        float s=red16(v0+v1), q=red16(v0*v0+v1*v1);
        if (l15==0){ int row=m*16+l4*4+r; sh_red[wave][row][0]=s; sh_red[wave][row][1]=q; }
      }
    __syncthreads();
    if (tid<32){
      float S=0.f,Q=0.f;
      #pragma unroll
      for (int w=0;w<8;w++){ S+=sh_red[w][tid][0]; Q+=sh_red[w][tid][1]; }
      float mu=S*(1.f/256.f), va=Q*(1.f/256.f)-mu*mu;
      sh_mu[tid]=mu; sh_rs[tid]=rsqrtf(va+1e-5f);
    }
    __syncthreads();
    float yv[2][2][4];
    #pragma unroll
    for (int m=0;m<2;m++)
      #pragma unroll
      for (int h=0;h<2;h++)
        #pragma unroll
        for (int r=0;r<4;r++){
          int row=m*16+l4*4+r;
          float x=(dacc[m][h][r]-sh_mu[row])*sh_rs[row];
          x = x*gdec[h]+bdec[h];
          yv[m][h][r]=gelu_f(x);
        }
    #pragma unroll
    for (int m=0;m<2;m++)
      #pragma unroll
      for (int r=0;r<4;r++){
        int row=m*16+l4*4+r;
        #pragma unroll
        for (int a=0;a<4;a++){
          float p = yv[m][0][r]*wd2f[a][0] + yv[m][1][r]*wd2f[a][1];
          p = red16(p);
          if (l15==0) sh_apart[wave][row][a]=p;
        }
      }
    __syncthreads();
    if (tid<128){
      int row=tid>>2, a=tid&3;
      float s=bd2v;
      #pragma unroll
      for (int w=0;w<8;w++) s+=sh_apart[w][row][a];
      bf16 ab=(bf16)s;
      sh_act[row*40+a]=ab;
      sh_actout[row*256 + t*4 + a]=ab;
    }
    __syncthreads();
  }

  // ---- flush actions (coalesced) + final h, c outputs ----
  if (f32f){
    float* o=(float*)outv;
    for (int i=tid;i<32*256;i+=512)
      o[(size_t)rbase*256 + ((i>>8)*256 + (i&255))] = b2f(((const short*)sh_actout)[i]);
    for (int i=tid;i<32*256;i+=512){
      int row=i>>8, col=i&255;
      int sw = swz(row,col);
      o[1048576 + (size_t)(rbase+row)*256 + col] = b2f(((const short*)sh_h0)[sw]);
      o[2097152 + (size_t)(rbase+row)*256 + col] = b2f(((const short*)sh_h1)[sw]);
    }
    #pragma unroll
    for (int m=0;m<2;m++)
      #pragma unroll
      for (int h=0;h<2;h++)
        #pragma unroll
        for (int r=0;r<4;r++){
          int row=m*16+l4*4+r, col=jw+h*16+l15;
          o[3145728 + (size_t)(rbase+row)*256 + col] = c0r[m][h][r];
          o[4194304 + (size_t)(rbase+row)*256 + col] = c1r[m][h][r];
        }
  } else {
    bf16* o=(bf16*)outv;
    for (int i=tid;i<32*256;i+=512)
      o[(size_t)rbase*256 + i] = sh_actout[i];
    for (int i=tid;i<32*256;i+=512){
      int row=i>>8, col=i&255;
      int sw = swz(row,col);
      o[1048576 + (size_t)(rbase+row)*256 + col] = sh_h0[sw];
      o[2097152 + (size_t)(rbase+row)*256 + col] = sh_h1[sw];
    }
    #pragma unroll
    for (int m=0;m<2;m++)
      #pragma unroll
      for (int h=0;h<2;h++)
        #pragma unroll
        for (int r=0;r<4;r++){
          int row=m*16+l4*4+r, col=jw+h*16+l15;
          o[3145728 + (size_t)(rbase+row)*256 + col] = (bf16)c0r[m][h][r];
          o[4194304 + (size_t)(rbase+row)*256 + col] = (bf16)c1r[m][h][r];
        }
  }
}

extern "C" void kernel_launch(void* const* d_in, const int* in_sizes, int n_in,
                              void* d_out, int out_size, void* d_ws, size_t ws_size,
                              hipStream_t stream) {
  int* flag = (int*)d_ws;                      // 16-byte header
  bf16* wsb = (bf16*)d_ws + 8;                 // canonical bf16 region (~3.4 MB)

  detect_dtype<<<1, 256, 0, stream>>>((const unsigned*)d_in[0], flag);

  canonize<<<(N_CANON+255)/256, 256, 0, stream>>>(
      d_in[0],  d_in[2],  d_in[3],  d_in[4],  d_in[5],
      d_in[6],  d_in[7],  d_in[8],  d_in[9],
      d_in[10], d_in[11], d_in[12], d_in[13],
      d_in[14], d_in[15], d_in[16], d_in[17],
      d_in[18], d_in[19],
      flag, wsb);

  policy_main<<<128, 512, 0, stream>>>(wsb, flag, d_out);
}

// Round 6
// 6267.634 us; speedup vs baseline: 1.2740x; 1.2179x over previous
//
#include <hip/hip_runtime.h>

typedef __bf16 bf16;
typedef short s16x4 __attribute__((ext_vector_type(4)));
typedef short s16x8 __attribute__((ext_vector_type(8)));
typedef float f32x4 __attribute__((ext_vector_type(4)));

#define MFMA16(a,b,c) __builtin_amdgcn_mfma_f32_16x16x32_bf16((a),(b),(c),0,0,0)
#define NBLOCKS 128

__device__ __forceinline__ float b2f(short s){
  union { float f; unsigned u; } v; v.u = ((unsigned)(unsigned short)s) << 16; return v.f;
}
__device__ __forceinline__ short f2b(float f){
  union { bf16 h; short s; } v; v.h = (bf16)f; return v.s;
}
__device__ __forceinline__ float sigm(float x){ return 1.f/(1.f+__expf(-x)); }
__device__ __forceinline__ float tanh_f(float x){ float e=__expf(2.f*x); return 1.f-2.f/(e+1.f); }
__device__ __forceinline__ float gelu_f(float x){ return 0.5f*x*(1.f+erff(x*0.70710678118654752f)); }
__device__ __forceinline__ float red16(float v){
  v += __shfl_xor(v,1); v += __shfl_xor(v,2); v += __shfl_xor(v,4); v += __shfl_xor(v,8);
  return v;
}

// ---- canonical bf16 workspace layout (element offsets within wsb) ----
#define OFF_STATE   0         // [4096][128]
#define OFF_WENC    524288    // [256][128]
#define OFF_BENC    557056
#define OFF_GENC    557312
#define OFF_BEENC   557568
#define OFF_WIH0E   557824    // [1024][256]  (Wih0[:, :256], prologue only)
#define OFF_W0E     819968    // [1024][288]  ([Whh0 | Wact(4) zero-pad to 32])
#define OFF_BIH0    1114880
#define OFF_BHH0    1115904
#define OFF_W1C     1116928   // [1024][512]  ([Wih1 | Whh1])
#define OFF_BIH1    1641216
#define OFF_BHH1    1642240
#define OFF_WD1     1643264   // [256][256]
#define OFF_BD1     1708800
#define OFF_GDEC    1709056
#define OFF_BEDEC   1709312
#define OFF_WD2     1709568   // [4][256]
#define OFF_BD2     1710592   // [4] (+4 pad)
#define N_CANON     1710600

__global__ __launch_bounds__(256) void detect_dtype(const unsigned* __restrict__ raw,
                                                    int* __restrict__ flag){
  unsigned w = raw[threadIdx.x];
  int e = (int)((w >> 7) & 0xFF);
  int looks_bf16 = (e >= 100 && e <= 130) ? 1 : 0;
  int cnt = __syncthreads_count(looks_bf16);
  if (threadIdx.x == 0) *flag = (cnt >= 128) ? 0 : 1;   // 1 => f32 buffers
}

__device__ __forceinline__ float ldf(const void* p, int i, int f32f){
  return f32f ? ((const float*)p)[i] : b2f(((const short*)p)[i]);
}

__global__ __launch_bounds__(256) void canonize(
    const void* state, const void* W_enc, const void* b_enc, const void* g_enc, const void* be_enc,
    const void* Wih0, const void* Whh0, const void* bih0, const void* bhh0,
    const void* Wih1, const void* Whh1, const void* bih1, const void* bhh1,
    const void* Wd1,  const void* bd1,  const void* g_dec, const void* be_dec,
    const void* Wd2,  const void* bd2,
    const int* __restrict__ flag, bf16* __restrict__ dst)
{
  int idx = blockIdx.x*256 + threadIdx.x;
  if (idx >= N_CANON) return;
  const int f = *flag;
  float v;
  if      (idx < OFF_WENC)  v = ldf(state, idx, f);
  else if (idx < OFF_BENC)  v = ldf(W_enc, idx-OFF_WENC, f);
  else if (idx < OFF_GENC)  v = ldf(b_enc, idx-OFF_BENC, f);
  else if (idx < OFF_BEENC) v = ldf(g_enc, idx-OFF_GENC, f);
  else if (idx < OFF_WIH0E) v = ldf(be_enc, idx-OFF_BEENC, f);
  else if (idx < OFF_W0E){  int j=idx-OFF_WIH0E; int r=j>>8, k=j&255; v = ldf(Wih0, r*260+k, f); }
  else if (idx < OFF_BIH0){ int j=idx-OFF_W0E;   int r=j/288, k=j-r*288;
                            v = (k<256) ? ldf(Whh0, r*256+k, f)
                              : (k<260) ? ldf(Wih0, r*260+256+(k-256), f) : 0.f; }
  else if (idx < OFF_BHH0)  v = ldf(bih0, idx-OFF_BIH0, f);
  else if (idx < OFF_W1C)   v = ldf(bhh0, idx-OFF_BHH0, f);
  else if (idx < OFF_BIH1){ int j=idx-OFF_W1C; int r=j>>9, k=j&511;
                            v = (k<256) ? ldf(Wih1, r*256+k, f) : ldf(Whh1, r*256+(k-256), f); }
  else if (idx < OFF_BHH1)  v = ldf(bih1, idx-OFF_BIH1, f);
  else if (idx < OFF_WD1)   v = ldf(bhh1, idx-OFF_BHH1, f);
  else if (idx < OFF_BD1)   v = ldf(Wd1,  idx-OFF_WD1, f);
  else if (idx < OFF_GDEC)  v = ldf(bd1,  idx-OFF_BD1, f);
  else if (idx < OFF_BEDEC) v = ldf(g_dec, idx-OFF_GDEC, f);
  else if (idx < OFF_WD2)   v = ldf(be_dec, idx-OFF_BEDEC, f);
  else if (idx < OFF_BD2)   v = ldf(Wd2, idx-OFF_WD2, f);
  else { int j=idx-OFF_BD2; v = (j<4) ? ldf(bd2, j, f) : 0.f; }
  dst[idx] = (bf16)v;
}

// swizzled element index into a [32][256] bf16 LDS tile (xor 16B blocks by row&7)
__device__ __forceinline__ int swz(int row, int colOrKe){ return row*256 + (colOrKe ^ ((row&7)<<3)); }

// load the 8 (g,h) B-fragments for one K-subtile
template<int STRIDE>
__device__ __forceinline__ void loadB8(s16x8* buf, const bf16* W, int cb, int koff){
  #pragma unroll
  for (int g=0;g<4;g++)
    #pragma unroll
    for (int h=0;h<2;h++)
      buf[g*2+h] = *(const s16x8*)(W + (size_t)(g*256 + cb + h*16)*STRIDE + koff);
}

__device__ __forceinline__ void mfma16x(f32x4 (&acc)[2][4][2], s16x8 a0, s16x8 a1, const s16x8* bb){
  #pragma unroll
  for (int g=0;g<4;g++)
    #pragma unroll
    for (int h=0;h<2;h++){
      acc[0][g][h]=MFMA16(a0,bb[g*2+h],acc[0][g][h]);
      acc[1][g][h]=MFMA16(a1,bb[g*2+h],acc[1][g][h]);
    }
}

__global__ __launch_bounds__(512, 1) void policy_main(
    const bf16* __restrict__ wsb, const int* __restrict__ flag,
    unsigned int* __restrict__ bar, void* __restrict__ outv)
{
  __shared__ __align__(16) bf16 sh_h0[32*256];        // swizzled
  __shared__ __align__(16) bf16 sh_h1[32*256];        // swizzled
  __shared__ __align__(16) bf16 sh_act[32*40];
  __shared__ __align__(16) s16x4 sh_zc[16][512];      // z0const, [frag][tid]
  __shared__ __align__(16) bf16 sh_actout[32*256];    // action buffer [row][t*4+a]
  __shared__ __align__(16) bf16 sh_emb[32*256];       // prologue only
  __shared__ __align__(16) bf16 sh_state[32*128];     // prologue only
  __shared__ float sh_red[8][32][2];
  __shared__ float sh_apart[8][32][4];
  __shared__ float sh_mu[32], sh_rs[32];

  const int tid  = threadIdx.x;
  const int wave = tid >> 6;
  const int lane = tid & 63;
  const int l15  = lane & 15;
  const int l4   = lane >> 4;
  const int jw   = wave * 32;
  const int cb   = jw + l15;            // base gate-col for this lane
  const int rbase = blockIdx.x * 32;
  const int f32f = *flag;

  const bf16* stateW = wsb + OFF_STATE;
  const bf16* W_enc  = wsb + OFF_WENC;
  const bf16* W0E    = wsb + OFF_W0E;
  const bf16* W1C    = wsb + OFF_W1C;
  const bf16* Wd1    = wsb + OFF_WD1;
  const bf16* Wih0E  = wsb + OFF_WIH0E;

  // ---- prologue: init LDS ----
  for (int i = tid; i < 32*256; i += 512) { sh_h0[i]=(bf16)0.f; sh_h1[i]=(bf16)0.f; }
  for (int i = tid; i < 32*40; i += 512) sh_act[i]=(bf16)0.f;
  for (int i = tid; i < 32*128; i += 512) sh_state[i] = stateW[rbase*128 + i];
  __syncthreads();

  // ---- encoder GEMM: emb = state @ W_enc^T + b_enc; LN; GELU ----
  f32x4 eacc[2][2];
  #pragma unroll
  for (int m=0;m<2;m++)
    #pragma unroll
    for (int h=0;h<2;h++) eacc[m][h]=(f32x4){0.f,0.f,0.f,0.f};
  #pragma unroll
  for (int kk=0;kk<4;kk++){
    int ke = kk*32 + l4*8;
    s16x8 a0 = *(const s16x8*)(sh_state + l15*128 + ke);
    s16x8 a1 = *(const s16x8*)(sh_state + (16+l15)*128 + ke);
    #pragma unroll
    for (int h=0;h<2;h++){
      s16x8 b = *(const s16x8*)(W_enc + (jw + h*16 + l15)*128 + ke);
      eacc[0][h] = MFMA16(a0,b,eacc[0][h]);
      eacc[1][h] = MFMA16(a1,b,eacc[1][h]);
    }
  }
  #pragma unroll
  for (int h=0;h<2;h++){
    float be = b2f(((const short*)(wsb+OFF_BENC))[jw + h*16 + l15]);
    #pragma unroll
    for (int m=0;m<2;m++)
      #pragma unroll
      for (int r=0;r<4;r++) eacc[m][h][r] += be;
  }
  #pragma unroll
  for (int m=0;m<2;m++)
    #pragma unroll
    for (int r=0;r<4;r++){
      float v0=eacc[m][0][r], v1=eacc[m][1][r];
      float s = red16(v0+v1), q = red16(v0*v0+v1*v1);
      if (l15==0){ int row=m*16+l4*4+r; sh_red[wave][row][0]=s; sh_red[wave][row][1]=q; }
    }
  __syncthreads();
  if (tid < 32){
    float S=0.f,Q=0.f;
    #pragma unroll
    for (int w=0;w<8;w++){ S+=sh_red[w][tid][0]; Q+=sh_red[w][tid][1]; }
    float mu=S*(1.f/256.f), va=Q*(1.f/256.f)-mu*mu;
    sh_mu[tid]=mu; sh_rs[tid]=rsqrtf(va+1e-5f);
  }
  __syncthreads();
  {
    float ge[2]={b2f(((const short*)(wsb+OFF_GENC))[jw+l15]), b2f(((const short*)(wsb+OFF_GENC))[jw+16+l15])};
    float be2[2]={b2f(((const short*)(wsb+OFF_BEENC))[jw+l15]), b2f(((const short*)(wsb+OFF_BEENC))[jw+16+l15])};
    #pragma unroll
    for (int m=0;m<2;m++)
      #pragma unroll
      for (int h=0;h<2;h++)
        #pragma unroll
        for (int r=0;r<4;r++){
          int row=m*16+l4*4+r, col=jw+h*16+l15;
          float x=(eacc[m][h][r]-sh_mu[row])*sh_rs[row];
          x = x*ge[h]+be2[h];
          sh_emb[row*256+col] = (bf16)gelu_f(x);
        }
  }
  __syncthreads();

  // ---- z0const = Wih0[:, :256] @ emb^T + (bih0+bhh0) -> sh_zc (packed bf16) ----
  {
    f32x4 zc[2][4][2];
    #pragma unroll
    for (int m=0;m<2;m++)
      #pragma unroll
      for (int g=0;g<4;g++)
        #pragma unroll
        for (int h=0;h<2;h++) zc[m][g][h]=(f32x4){0.f,0.f,0.f,0.f};
    #pragma unroll
    for (int kk=0;kk<8;kk++){
      int ke=kk*32+l4*8;
      s16x8 a0=*(const s16x8*)(sh_emb + l15*256 + ke);
      s16x8 a1=*(const s16x8*)(sh_emb + (16+l15)*256 + ke);
      #pragma unroll
      for (int g=0;g<4;g++)
        #pragma unroll
        for (int h=0;h<2;h++){
          int c=g*256+cb+h*16;
          s16x8 b = *(const s16x8*)(Wih0E + c*256 + ke);
          zc[0][g][h]=MFMA16(a0,b,zc[0][g][h]);
          zc[1][g][h]=MFMA16(a1,b,zc[1][g][h]);
        }
    }
    #pragma unroll
    for (int g=0;g<4;g++)
      #pragma unroll
      for (int h=0;h<2;h++){
        int c=g*256+cb+h*16;
        float bb=b2f(((const short*)(wsb+OFF_BIH0))[c])+b2f(((const short*)(wsb+OFF_BHH0))[c]);
        #pragma unroll
        for (int m=0;m<2;m++){
          s16x4 pk;
          #pragma unroll
          for (int r=0;r<4;r++) pk[r]=f2b(zc[m][g][h][r]+bb);
          sh_zc[m*8+g*2+h][tid]=pk;
        }
      }
  }

  // ---- persistent per-thread parameters ----
  float bz1f[4][2];
  #pragma unroll
  for (int g=0;g<4;g++)
    #pragma unroll
    for (int h=0;h<2;h++){
      int c=g*256+cb+h*16;
      bz1f[g][h]=b2f(((const short*)(wsb+OFF_BIH1))[c])+b2f(((const short*)(wsb+OFF_BHH1))[c]);
    }
  float bd1f[2]={b2f(((const short*)(wsb+OFF_BD1))[jw+l15]), b2f(((const short*)(wsb+OFF_BD1))[jw+16+l15])};
  float gdec[2]={b2f(((const short*)(wsb+OFF_GDEC))[jw+l15]), b2f(((const short*)(wsb+OFF_GDEC))[jw+16+l15])};
  float bdec[2]={b2f(((const short*)(wsb+OFF_BEDEC))[jw+l15]), b2f(((const short*)(wsb+OFF_BEDEC))[jw+16+l15])};
  float wd2f[4][2];
  #pragma unroll
  for (int a=0;a<4;a++){
    wd2f[a][0]=b2f(((const short*)(wsb+OFF_WD2))[a*256+jw+l15]);
    wd2f[a][1]=b2f(((const short*)(wsb+OFF_WD2))[a*256+jw+16+l15]);
  }
  float bd2v = b2f(((const short*)(wsb+OFF_BD2))[tid&3]);
  float c0r[2][2][4], c1r[2][2][4];
  #pragma unroll
  for (int m=0;m<2;m++)
    #pragma unroll
    for (int h=0;h<2;h++)
      #pragma unroll
      for (int r=0;r<4;r++){ c0r[m][h][r]=0.f; c1r[m][h][r]=0.f; }
  __syncthreads();

  // ---- weight-fragment double buffers + first prefetch (L0 kk=0) ----
  s16x8 bb0[8], bb1[8];
  const int koff = l4*8;
  loadB8<288>(bb0, W0E, cb, koff);

  // ================= 64 recurrent steps =================
  #pragma unroll 1
  for (int t=0;t<64;++t){
    // ---- soft lockstep barrier (performance only; bounded spin; no data deps) ----
    if (tid==0){
      __hip_atomic_fetch_add(bar, 1u, __ATOMIC_RELAXED, __HIP_MEMORY_SCOPE_AGENT);
      unsigned target = (unsigned)NBLOCKS*(unsigned)(t+1);
      int guard = 0;
      while (__hip_atomic_load(bar, __ATOMIC_RELAXED, __HIP_MEMORY_SCOPE_AGENT) < target
             && guard < 4096){
        __builtin_amdgcn_s_sleep(8);
        ++guard;
      }
    }
    __syncthreads();

    // ---------- layer0: z0 = z0const + [Whh0|Wact] @ [h0|act] ----------
    f32x4 acc[2][4][2];
    #pragma unroll
    for (int m=0;m<2;m++)
      #pragma unroll
      for (int g=0;g<4;g++)
        #pragma unroll
        for (int h=0;h<2;h++){
          s16x4 z=sh_zc[m*8+g*2+h][tid];
          acc[m][g][h]=(f32x4){b2f(z[0]),b2f(z[1]),b2f(z[2]),b2f(z[3])};
        }
    #pragma unroll
    for (int kk=0;kk<9;kk++){
      if (kk+1 < 9) loadB8<288>(((kk&1)?bb0:bb1), W0E, cb, (kk+1)*32+koff);
      s16x8 a0,a1;
      if (kk<8){
        int ke=kk*32+koff;
        a0=*(const s16x8*)(sh_h0 + swz(l15,ke));
        a1=*(const s16x8*)(sh_h0 + swz(16+l15,ke));
      } else {
        a0=*(const s16x8*)(sh_act + l15*40 + koff);
        a1=*(const s16x8*)(sh_act + (16+l15)*40 + koff);
      }
      mfma16x(acc, a0, a1, ((kk&1)?bb1:bb0));
    }
    loadB8<512>(bb0, W1C, cb, koff);           // prefetch layer1 kk=0 (hidden under gates+barriers)
    float hnew[2][2][4];
    #pragma unroll
    for (int m=0;m<2;m++)
      #pragma unroll
      for (int h=0;h<2;h++)
        #pragma unroll
        for (int r=0;r<4;r++){
          float cn = sigm(acc[m][1][h][r])*c0r[m][h][r] + sigm(acc[m][0][h][r])*tanh_f(acc[m][2][h][r]);
          c0r[m][h][r]=cn;
          hnew[m][h][r]=sigm(acc[m][3][h][r])*tanh_f(cn);
        }
    __syncthreads();
    #pragma unroll
    for (int m=0;m<2;m++)
      #pragma unroll
      for (int h=0;h<2;h++)
        #pragma unroll
        for (int r=0;r<4;r++){
          int row=m*16+l4*4+r, col=jw+h*16+l15;
          sh_h0[swz(row,col)] = (bf16)hnew[m][h][r];
        }
    __syncthreads();

    // ---------- layer1: z1 = bz1 + [Wih1|Whh1] @ [h0|h1] ----------
    #pragma unroll
    for (int m=0;m<2;m++)
      #pragma unroll
      for (int g=0;g<4;g++)
        #pragma unroll
        for (int h=0;h<2;h++){
          float bbv=bz1f[g][h];
          acc[m][g][h]=(f32x4){bbv,bbv,bbv,bbv};
        }
    #pragma unroll
    for (int kk=0;kk<16;kk++){
      if (kk+1 < 16) loadB8<512>(((kk&1)?bb0:bb1), W1C, cb, (kk+1)*32+koff);
      s16x8 a0,a1;
      if (kk<8){
        int ke=kk*32+koff;
        a0=*(const s16x8*)(sh_h0 + swz(l15,ke));
        a1=*(const s16x8*)(sh_h0 + swz(16+l15,ke));
      } else {
        int ke=(kk-8)*32+koff;
        a0=*(const s16x8*)(sh_h1 + swz(l15,ke));
        a1=*(const s16x8*)(sh_h1 + swz(16+l15,ke));
      }
      mfma16x(acc, a0, a1, ((kk&1)?bb1:bb0));
    }
    // prefetch ALL of this wave's Wd1 fragments (16) — hidden under gates+barriers
    #pragma unroll
    for (int kk=0;kk<8;kk++)
      #pragma unroll
      for (int hh=0;hh<2;hh++){
        int c = cb + hh*16;
        ((kk<4)?bb0:bb1)[(kk&3)*2+hh] = *(const s16x8*)(Wd1 + c*256 + kk*32 + koff);
      }
    #pragma unroll
    for (int m=0;m<2;m++)
      #pragma unroll
      for (int h=0;h<2;h++)
        #pragma unroll
        for (int r=0;r<4;r++){
          float cn = sigm(acc[m][1][h][r])*c1r[m][h][r] + sigm(acc[m][0][h][r])*tanh_f(acc[m][2][h][r]);
          c1r[m][h][r]=cn;
          hnew[m][h][r]=sigm(acc[m][3][h][r])*tanh_f(cn);
        }
    __syncthreads();
    #pragma unroll
    for (int m=0;m<2;m++)
      #pragma unroll
      for (int h=0;h<2;h++)
        #pragma unroll
        for (int r=0;r<4;r++){
          int row=m*16+l4*4+r, col=jw+h*16+l15;
          sh_h1[swz(row,col)] = (bf16)hnew[m][h][r];
        }
    __syncthreads();

    // ---------- decoder: d1 = bd1 + Wd1 @ h1_new (frags already in regs) ----------
    f32x4 dacc[2][2];
    #pragma unroll
    for (int m=0;m<2;m++)
      #pragma unroll
      for (int h=0;h<2;h++){
        float bbv=bd1f[h];
        dacc[m][h]=(f32x4){bbv,bbv,bbv,bbv};
      }
    #pragma unroll
    for (int kk=0;kk<8;kk++){
      int ke=kk*32+koff;
      s16x8 a0=*(const s16x8*)(sh_h1 + swz(l15,ke));
      s16x8 a1=*(const s16x8*)(sh_h1 + swz(16+l15,ke));
      #pragma unroll
      for (int hh=0;hh<2;hh++){
        s16x8 b = ((kk<4)?bb0:bb1)[(kk&3)*2+hh];
        dacc[0][hh]=MFMA16(a0,b,dacc[0][hh]);
        dacc[1][hh]=MFMA16(a1,b,dacc[1][hh]);
      }
    }
    loadB8<288>(bb0, W0E, cb, koff);           // prefetch next step's L0 kk=0
    #pragma unroll
    for (int m=0;m<2;m++)
      #pragma unroll
      for (int r=0;r<4;r++){
        float v0=dacc[m][0][r], v1=dacc[m][1][r];
        float s=red16(v0+v1), q=red16(v0*v0+v1*v1);
        if (l15==0){ int row=m*16+l4*4+r; sh_red[wave][row][0]=s; sh_red[wave][row][1]=q; }
      }
    __syncthreads();
    if (tid<32){
      float S=0.f,Q=0.f;
      #pragma unroll
      for (int w=0;w<8;w++){ S+=sh_red[w][tid][0]; Q+=sh_red[w][tid][1]; }
      float mu=S*(1.f/256.f), va=Q*(1.f/256.f)-mu*mu;
      sh_mu[tid]=mu; sh_rs[tid]=rsqrtf(va+1e-5f);
    }
    __syncthreads();
    float yv[2][2][4];
    #pragma unroll
    for (int m=0;m<2;m++)
      #pragma unroll
      for (int h=0;h<2;h++)
        #pragma unroll
        for (int r=0;r<4;r++){
          int row=m*16+l4*4+r;
          float x=(dacc[m][h][r]-sh_mu[row])*sh_rs[row];
          x = x*gdec[h]+bdec[h];
          yv[m][h][r]=gelu_f(x);
        }
    #pragma unroll
    for (int m=0;m<2;m++)
      #pragma unroll
      for (int r=0;r<4;r++){
        int row=m*16+l4*4+r;
        #pragma unroll
        for (int a=0;a<4;a++){
          float p = yv[m][0][r]*wd2f[a][0] + yv[m][1][r]*wd2f[a][1];
          p = red16(p);
          if (l15==0) sh_apart[wave][row][a]=p;
        }
      }
    __syncthreads();
    if (tid<128){
      int row=tid>>2, a=tid&3;
      float s=bd2v;
      #pragma unroll
      for (int w=0;w<8;w++) s+=sh_apart[w][row][a];
      bf16 ab=(bf16)s;
      sh_act[row*40+a]=ab;
      sh_actout[row*256 + t*4 + a]=ab;
    }
    __syncthreads();
  }

  // ---- flush actions (coalesced) + final h, c outputs ----
  if (f32f){
    float* o=(float*)outv;
    for (int i=tid;i<32*256;i+=512)
      o[(size_t)rbase*256 + ((i>>8)*256 + (i&255))] = b2f(((const short*)sh_actout)[i]);
    for (int i=tid;i<32*256;i+=512){
      int row=i>>8, col=i&255;
      int sw = swz(row,col);
      o[1048576 + (size_t)(rbase+row)*256 + col] = b2f(((const short*)sh_h0)[sw]);
      o[2097152 + (size_t)(rbase+row)*256 + col] = b2f(((const short*)sh_h1)[sw]);
    }
    #pragma unroll
    for (int m=0;m<2;m++)
      #pragma unroll
      for (int h=0;h<2;h++)
        #pragma unroll
        for (int r=0;r<4;r++){
          int row=m*16+l4*4+r, col=jw+h*16+l15;
          o[3145728 + (size_t)(rbase+row)*256 + col] = c0r[m][h][r];
          o[4194304 + (size_t)(rbase+row)*256 + col] = c1r[m][h][r];
        }
  } else {
    bf16* o=(bf16*)outv;
    for (int i=tid;i<32*256;i+=512)
      o[(size_t)rbase*256 + i] = sh_actout[i];
    for (int i=tid;i<32*256;i+=512){
      int row=i>>8, col=i&255;
      int sw = swz(row,col);
      o[1048576 + (size_t)(rbase+row)*256 + col] = sh_h0[sw];
      o[2097152 + (size_t)(rbase+row)*256 + col] = sh_h1[sw];
    }
    #pragma unroll
    for (int m=0;m<2;m++)
      #pragma unroll
      for (int h=0;h<2;h++)
        #pragma unroll
        for (int r=0;r<4;r++){
          int row=m*16+l4*4+r, col=jw+h*16+l15;
          o[3145728 + (size_t)(rbase+row)*256 + col] = (bf16)c0r[m][h][r];
          o[4194304 + (size_t)(rbase+row)*256 + col] = (bf16)c1r[m][h][r];
        }
  }
}

extern "C" void kernel_launch(void* const* d_in, const int* in_sizes, int n_in,
                              void* d_out, int out_size, void* d_ws, size_t ws_size,
                              hipStream_t stream) {
  unsigned int* bar = (unsigned int*)d_ws;                 // [0,256): barrier counter
  int* flag = (int*)((char*)d_ws + 256);                   // [256,512): dtype flag
  bf16* wsb = (bf16*)((char*)d_ws + 512);                  // canonical bf16 region (~3.4 MB)

  hipMemsetAsync(d_ws, 0, 256, stream);                    // zero the barrier counter

  detect_dtype<<<1, 256, 0, stream>>>((const unsigned*)d_in[0], flag);

  canonize<<<(N_CANON+255)/256, 256, 0, stream>>>(
      d_in[0],  d_in[2],  d_in[3],  d_in[4],  d_in[5],
      d_in[6],  d_in[7],  d_in[8],  d_in[9],
      d_in[10], d_in[11], d_in[12], d_in[13],
      d_in[14], d_in[15], d_in[16], d_in[17],
      d_in[18], d_in[19],
      flag, wsb);

  policy_main<<<NBLOCKS, 512, 0, stream>>>(wsb, flag, bar, d_out);
}